// Round 6
// baseline (371.173 us; speedup 1.0000x reference)
//
#include <hip/hip_runtime.h>
#include <hip/hip_bf16.h>

#define B_   4
#define IC   64
#define OC   128
#define HH   128
#define WW   128
#define HP   130      // padded H/W for sampling
#define XOF  384      // x_off spatial (128*3)
#define XPAD 388      // padded x-dim of granule layout
#define OH2  382      // final output spatial

typedef __attribute__((ext_vector_type(4))) float f32x4;
typedef __attribute__((ext_vector_type(8))) __bf16 bf16x8;
typedef __attribute__((ext_vector_type(8))) unsigned short us8;
typedef __attribute__((ext_vector_type(4), aligned(4))) float f32x4u;

__device__ __forceinline__ void gload16(const void* gsrc, void* ldst) {
    __builtin_amdgcn_global_load_lds(
        (const __attribute__((address_space(1))) void*)gsrc,
        (__attribute__((address_space(3))) void*)ldst, 16, 0, 0);
}

// ---------------------------------------------------------------------------
// Kernel A1 v3: offset conv partials — 64-wide coalesced tiles.
// Block = 64 px x 4 rows; z = icg*4 + b (8 ic per block) -> 2x32x32 = 2048
// blocks = 8/CU. Each wave's loads AND stores are single contiguous 256B
// segments (vs the R5 16x16 tile whose every memory op touched 4 disjoint
// segments). Same math, same partial layout as R5.
// part[icg][b][co][py][px]
// ---------------------------------------------------------------------------
__global__ __launch_bounds__(256) void offset_part8w(const float* __restrict__ x,
                                                     const float* __restrict__ w_p,
                                                     float* __restrict__ part) {
    int z   = blockIdx.z;
    int icg = z >> 2, b = z & 3;
    int ic0 = icg * 8;

    int tid = threadIdx.x;
    int lx  = tid & 63;
    int ly  = tid >> 6;
    int px  = blockIdx.x * 64 + lx;
    int py  = blockIdx.y * 4 + ly;

    float acc[18];
#pragma unroll
    for (int co = 0; co < 18; ++co) acc[co] = 0.f;

    const float* xb = x + ((size_t)b * IC + ic0) * HH * WW;

#pragma unroll
    for (int ic = 0; ic < 8; ++ic) {
        const float* xc = xb + (size_t)ic * HH * WW;
        float xv[9];
#pragma unroll
        for (int ky = 0; ky < 3; ++ky) {
            int yy = py + ky - 1;
            bool yok = (yy >= 0) && (yy < HH);
#pragma unroll
            for (int kx = 0; kx < 3; ++kx) {
                int xx = px + kx - 1;
                bool ok = yok && (xx >= 0) && (xx < WW);
                xv[ky * 3 + kx] = ok ? xc[yy * WW + xx] : 0.f;
            }
        }
#pragma unroll
        for (int co = 0; co < 18; ++co) {
            const float* wrow = w_p + ((size_t)co * IC + ic0 + ic) * 9;
#pragma unroll
            for (int k = 0; k < 9; ++k)
                acc[co] = fmaf(wrow[k], xv[k], acc[co]);
        }
    }

    float* pp = part + (size_t)z * 18 * HH * WW + (size_t)py * WW + px;
#pragma unroll
    for (int co = 0; co < 18; ++co) pp[(size_t)co * HH * WW] = acc[co];
}

// ---------------------------------------------------------------------------
// Kernel A2 (byte-identical to R5): merge 8 partials + bias.
// ---------------------------------------------------------------------------
__global__ __launch_bounds__(256) void merge_off8(const float* __restrict__ part,
                                                  const float* __restrict__ b_p,
                                                  float* __restrict__ off) {
    const int S = 18 * HH * WW;          // per (icg,b) plane group
    const int T = 4 * S;                 // stride between icg groups
    int t = blockIdx.x * 256 + threadIdx.x;   // 4*S exact
    int b = t / S;
    int rem = t - b * S;
    int co = rem >> 14;                  // HH*WW = 16384
    float s = b_p[co];
#pragma unroll
    for (int g = 0; g < 8; ++g)
        s += part[(size_t)g * T + (size_t)b * S + rem];
    off[t] = s;
}

// ---------------------------------------------------------------------------
// Kernel P (byte-identical to R5): weights -> bf16 K-step tiles.
// ---------------------------------------------------------------------------
__global__ __launch_bounds__(256) void prep_w(const float* __restrict__ wc,
                                              unsigned short* __restrict__ Bt) {
    int t = blockIdx.x * 256 + threadIdx.x;
    if (t >= 18 * 4 * 128 * 8) return;
    int e  = t & 7;
    int oc = (t >> 3) & 127;
    int kg = (t >> 10) & 3;
    int s  = t >> 12;
    int ic = ((s & 1) << 5) + (kg << 3) + e;
    int kpos = s >> 1;
    int ky = kpos / 3, kx = kpos % 3;
    float v = wc[(((size_t)oc * IC + ic) * 3 + ky) * 3 + kx];
    __hip_bfloat16 h = __float2bfloat16(v);
    Bt[t] = reinterpret_cast<unsigned short&>(h);
}

// ---------------------------------------------------------------------------
// Kernel B (byte-identical to R5): bilinear sampling -> granule layout.
// ---------------------------------------------------------------------------
__global__ __launch_bounds__(256) void sample_g(const float* __restrict__ x,
                                                const float* __restrict__ off,
                                                unsigned short* __restrict__ xoff,
                                                int b0, int nwg) {
    int orig = blockIdx.x;
    int chunk = nwg >> 3;
    int wg = (orig & 7) * chunk + (orig >> 3);

    int xt  = wg % 12;
    int tmp = wg / 12;
    int yy  = tmp % XOF;
    int bl  = tmp / XOF;
    int b   = b0 + bl;
    int xx0 = xt * 32;

    int t  = threadIdx.x;
    int xl = t & 31;
    int cg = t >> 5;
    int xx = xx0 + xl;

    int j = xx / 3, kw = xx % 3;
    int i = yy / 3, kh = yy % 3;
    int n = kh * 3 + kw;

    const float* offb = off + (size_t)b * 18 * HH * WW + (size_t)i * WW + j;
    float offr = offb[(size_t)n * HH * WW];
    float offc = offb[(size_t)(n + 9) * HH * WW];

    float pr = (float)(i + kh) + offr;
    float pc = (float)(j + kw) + offc;

    float r0f = floorf(pr), c0f = floorf(pc);
    int r0 = min(max((int)r0f, 0), HP - 1);
    int c0 = min(max((int)c0f, 0), HP - 1);
    int r1 = min(max((int)(r0f + 1.f), 0), HP - 1);
    int c1 = min(max((int)(c0f + 1.f), 0), HP - 1);

    float prc = fminf(fmaxf(pr, 0.f), (float)(HP - 1));
    float pcc = fminf(fmaxf(pc, 0.f), (float)(HP - 1));

    float glt = (1.f + ((float)r0 - prc)) * (1.f + ((float)c0 - pcc));
    float grb = (1.f - ((float)r1 - prc)) * (1.f - ((float)c1 - pcc));
    float glb = (1.f + ((float)r0 - prc)) * (1.f - ((float)c1 - pcc));
    float grt = (1.f - ((float)r1 - prc)) * (1.f + ((float)c0 - pcc));

    int rr0 = r0 - 1, cc0 = c0 - 1, rr1 = r1 - 1, cc1 = c1 - 1;
    bool r0ok = (rr0 >= 0) && (rr0 < HH);
    bool r1ok = (rr1 >= 0) && (rr1 < HH);
    bool c0ok = (cc0 >= 0) && (cc0 < WW);
    bool c1ok = (cc1 >= 0) && (cc1 < WW);

    float wlt = (r0ok && c0ok) ? glt : 0.f;
    float wrb = (r1ok && c1ok) ? grb : 0.f;
    float wlb = (r0ok && c1ok) ? glb : 0.f;
    float wrt = (r1ok && c0ok) ? grt : 0.f;
    int olt = (r0ok && c0ok) ? (rr0 * WW + cc0) : 0;
    int orb = (r1ok && c1ok) ? (rr1 * WW + cc1) : 0;
    int olb = (r0ok && c1ok) ? (rr0 * WW + cc1) : 0;
    int ort = (r1ok && c0ok) ? (rr1 * WW + cc0) : 0;

    const float* xg = x + ((size_t)b * IC + cg * 8) * HH * WW;

    us8 res;
#pragma unroll
    for (int e = 0; e < 8; ++e) {
        const float* xc = xg + (size_t)e * HH * WW;
        float v = wlt * xc[olt] + wrb * xc[orb] + wlb * xc[olb] + wrt * xc[ort];
        __hip_bfloat16 h = __float2bfloat16(v);
        res[e] = reinterpret_cast<unsigned short&>(h);
    }

    size_t di = ((((size_t)bl * XOF + yy) * 8 + cg) * XPAD + xx) * 8;
    *(us8*)(xoff + di) = res;
}

// ---------------------------------------------------------------------------
// Kernel C (byte-identical to R5/R4): bf16 MFMA implicit-GEMM conv.
// ---------------------------------------------------------------------------
__global__ __launch_bounds__(256) void conv2_mfma(const unsigned short* __restrict__ xoff,
                                                  const unsigned short* __restrict__ Bt,
                                                  float* __restrict__ out,
                                                  int b0, int nwg) {
    __shared__ __align__(16) char lds[40960];
    // A slab buf: [cg:4][px:192][16B] = 12288 B at buf*12288
    // B buf:      [kg:4][oc:128][16B] =  8192 B at 24576 + buf*8192

    // bijective XCD-chunk swizzle (m204)
    int orig = blockIdx.x;
    int q = nwg >> 3, r = nwg & 7;
    int xcd = orig & 7, loc = orig >> 3;
    int wgid = (xcd < r ? xcd * (q + 1) : r * (q + 1) + (xcd - r) * q) + loc;

    int xt  = wgid % 3;
    int tmp = wgid / 3;
    int oy  = tmp % OH2;
    int bl  = tmp / OH2;
    int x0  = xt << 7;

    int tid  = threadIdx.x;
    int wave = tid >> 6, lane = tid & 63;
    int wm = wave >> 1;            // px half
    int wn = wave & 1;             // oc half
    int lr = lane & 15, lc = lane >> 4;

    const char* xb = (const char*)xoff + (size_t)bl * ((size_t)XOF * 8 * XPAD * 16);
    const char* bt = (const char*)Bt;

    f32x4 acc[4][4];
#pragma unroll
    for (int mf = 0; mf < 4; ++mf)
#pragma unroll
        for (int nf = 0; nf < 4; ++nf)
            acc[mf][nf] = (f32x4){0.f, 0.f, 0.f, 0.f};

    auto stageA = [&](int abuf, int s6, int third) {
        int ky  = s6 >> 1;
        int ich = s6 & 1;
        int L   = third * 4 + wave;
        int cg  = L / 3, seg = L % 3;
        const char* src = xb +
            (((size_t)(oy + ky) * 8 + ich * 4 + cg) * XPAD + x0 + seg * 64 + lane) * 16;
        char* dst = lds + abuf * 12288 + (cg * 192 + seg * 64) * 16;
        gload16(src, dst);
    };
    auto stageA_full = [&](int abuf, int s6) {
#pragma unroll
        for (int qq = 0; qq < 3; ++qq) {
            int ky  = s6 >> 1;
            int ich = s6 & 1;
            int L   = wave * 3 + qq;
            int cg  = L / 3, seg = L % 3;
            const char* src = xb +
                (((size_t)(oy + ky) * 8 + ich * 4 + cg) * XPAD + x0 + seg * 64 + lane) * 16;
            char* dst = lds + abuf * 12288 + (cg * 192 + seg * 64) * 16;
            gload16(src, dst);
        }
    };
    auto stageB = [&](int bbuf, int t) {
        int s6 = t / 3, kx = t % 3;
        int sB = ((s6 >> 1) * 3 + kx) * 2 + (s6 & 1);
        const char* bsrc = bt + (size_t)sB * 8192;
#pragma unroll
        for (int g2 = 0; g2 < 2; ++g2) {
            int g = wave * 2 + g2;
            gload16(bsrc + (size_t)g * 1024 + lane * 16,
                    lds + 24576 + bbuf * 8192 + g * 1024);
        }
    };

    auto compute = [&](int abuf, int bbuf, int kx) {
        const char* abase = lds + abuf * 12288;
        const char* bbase = lds + 24576 + bbuf * 8192;
        bf16x8 af[4], bfr[4];
#pragma unroll
        for (int mf = 0; mf < 4; ++mf)
            af[mf] = *(const bf16x8*)(abase +
                (lc * 192 + wm * 64 + mf * 16 + lr + kx) * 16);
#pragma unroll
        for (int nf = 0; nf < 4; ++nf)
            bfr[nf] = *(const bf16x8*)(bbase +
                (lc * 128 + wn * 64 + nf * 16 + lr) * 16);
#pragma unroll
        for (int mf = 0; mf < 4; ++mf)
#pragma unroll
            for (int nf = 0; nf < 4; ++nf)
                acc[mf][nf] = __builtin_amdgcn_mfma_f32_16x16x32_bf16(
                    af[mf], bfr[nf], acc[mf][nf], 0, 0, 0);
    };

    stageA_full(0, 0);
    stageB(0, 0);
    __syncthreads();

    int abuf = 0, bbuf = 0;
    for (int t = 0; t < 18; ++t) {
        int s6 = t / 3, kx = t % 3;
        if (t + 1 < 18) stageB(bbuf ^ 1, t + 1);
        if (s6 + 1 < 6) stageA(abuf ^ 1, s6 + 1, kx);
        compute(abuf, bbuf, kx);
        __syncthreads();
        bbuf ^= 1;
        if (kx == 2) abuf ^= 1;
    }

    int b = b0 + bl;
#pragma unroll
    for (int mf = 0; mf < 4; ++mf) {
        int ox0 = x0 + wm * 64 + mf * 16 + (lc << 2);
#pragma unroll
        for (int nf = 0; nf < 4; ++nf) {
            int oc = wn * 64 + nf * 16 + lr;
            float* po = out + (((size_t)b * OC + oc) * OH2 + oy) * OH2 + ox0;
            if (ox0 + 3 < OH2) {
                *(f32x4u*)po = acc[mf][nf];
            } else {
#pragma unroll
                for (int rr = 0; rr < 4; ++rr)
                    if (ox0 + rr < OH2) po[rr] = acc[mf][nf][rr];
            }
        }
    }
}

// ---------------------------------------------------------------------------
extern "C" void kernel_launch(void* const* d_in, const int* in_sizes, int n_in,
                              void* d_out, int out_size, void* d_ws, size_t ws_size,
                              hipStream_t stream) {
    const float* x      = (const float*)d_in[0];
    const float* w_p    = (const float*)d_in[1];
    const float* b_p    = (const float*)d_in[2];
    const float* w_conv = (const float*)d_in[3];
    float* out = (float*)d_out;

    const size_t offElems  = (size_t)B_ * 18 * HH * WW;          // f32
    const size_t partElems = 8 * offElems;                       // f32
    const size_t btElems   = (size_t)18 * 4 * 128 * 8;           // bf16
    const size_t xofElems  = (size_t)XOF * 8 * XPAD * 8;         // bf16 per batch
    const size_t slack     = 16384;

    float* off  = (float*)d_ws;
    float* part = off + offElems;
    unsigned short* Bt   = (unsigned short*)(part + partElems);
    unsigned short* xoff = Bt + btElems;

    const size_t headBytes = (offElems + partElems) * 4 + btElems * 2;
    const bool allBatch = ws_size >= headBytes + 4 * xofElems * 2 + slack;

    prep_w<<<(int)((btElems + 255) / 256), 256, 0, stream>>>(w_conv, Bt);

    dim3 og(2, 32, 32);
    offset_part8w<<<og, 256, 0, stream>>>(x, w_p, part);
    merge_off8<<<(int)(offElems / 256), 256, 0, stream>>>(part, b_p, off);

    if (allBatch) {
        int snwg = 12 * XOF * B_;                 // 18432
        sample_g<<<snwg, 256, 0, stream>>>(x, off, xoff, 0, snwg);
        int cnwg = 3 * OH2 * B_;                  // 4584
        conv2_mfma<<<cnwg, 256, 0, stream>>>(xoff, Bt, out, 0, cnwg);
    } else {
        for (int b = 0; b < B_; ++b) {
            int snwg = 12 * XOF;                  // 4608
            sample_g<<<snwg, 256, 0, stream>>>(x, off, xoff, b, snwg);
            int cnwg = 3 * OH2;                   // 1146
            conv2_mfma<<<cnwg, 256, 0, stream>>>(xoff, Bt, out, b, cnwg);
        }
    }
}

// Round 7
// 368.110 us; speedup vs baseline: 1.0083x; 1.0083x over previous
//
#include <hip/hip_runtime.h>
#include <hip/hip_bf16.h>

#define B_   4
#define IC   64
#define OC   128
#define HH   128
#define WW   128
#define HP   130      // padded H/W for sampling
#define XOF  384      // x_off spatial (128*3)
#define XPAD 388      // padded x-dim of granule layout
#define OH2  382      // final output spatial

typedef __attribute__((ext_vector_type(4))) float f32x4;
typedef __attribute__((ext_vector_type(8))) __bf16 bf16x8;
typedef __attribute__((ext_vector_type(8))) unsigned short us8;
typedef __attribute__((ext_vector_type(4), aligned(4))) float f32x4u;

__device__ __forceinline__ void gload16(const void* gsrc, void* ldst) {
    __builtin_amdgcn_global_load_lds(
        (const __attribute__((address_space(1))) void*)gsrc,
        (__attribute__((address_space(3))) void*)ldst, 16, 0, 0);
}

// ---------------------------------------------------------------------------
// Kernel A (R1-proven version): offset conv, thread-per-pixel, all 64 ic.
// No LDS, no barriers, no partials: 18 independent acc chains provide the
// ILP to hide load latency even at 1 block/CU. Total traffic ~55 MB vs the
// R5/R6 partial scheme's ~320 MB.
// ---------------------------------------------------------------------------
__global__ __launch_bounds__(256) void offset_conv(const float* __restrict__ x,
                                                   const float* __restrict__ w_p,
                                                   const float* __restrict__ b_p,
                                                   float* __restrict__ off) {
    int t  = blockIdx.x * 256 + threadIdx.x;       // 4*128*128 = 65536 exact
    int px = t % WW;
    int py = (t / WW) % HH;
    int b  = t / (WW * HH);

    float acc[18];
#pragma unroll
    for (int co = 0; co < 18; ++co) acc[co] = b_p[co];

    const float* xb = x + (size_t)b * IC * HH * WW;
    for (int ci = 0; ci < IC; ++ci) {
        const float* xc = xb + (size_t)ci * HH * WW;
        float xv[9];
#pragma unroll
        for (int ky = 0; ky < 3; ++ky) {
            int yy = py + ky - 1;
            bool yok = (yy >= 0) && (yy < HH);
#pragma unroll
            for (int kx = 0; kx < 3; ++kx) {
                int xx = px + kx - 1;
                bool ok = yok && (xx >= 0) && (xx < WW);
                xv[ky * 3 + kx] = ok ? xc[yy * WW + xx] : 0.f;
            }
        }
#pragma unroll
        for (int co = 0; co < 18; ++co) {
            const float* wrow = w_p + ((size_t)co * IC + ci) * 9;
#pragma unroll
            for (int k = 0; k < 9; ++k)
                acc[co] = fmaf(wrow[k], xv[k], acc[co]);
        }
    }

    float* ob = off + (size_t)b * 18 * HH * WW + (size_t)py * WW + px;
#pragma unroll
    for (int co = 0; co < 18; ++co) ob[(size_t)co * HH * WW] = acc[co];
}

// ---------------------------------------------------------------------------
// Kernel P (byte-identical to R5/R6): weights -> bf16 K-step tiles.
// ---------------------------------------------------------------------------
__global__ __launch_bounds__(256) void prep_w(const float* __restrict__ wc,
                                              unsigned short* __restrict__ Bt) {
    int t = blockIdx.x * 256 + threadIdx.x;
    if (t >= 18 * 4 * 128 * 8) return;
    int e  = t & 7;
    int oc = (t >> 3) & 127;
    int kg = (t >> 10) & 3;
    int s  = t >> 12;
    int ic = ((s & 1) << 5) + (kg << 3) + e;
    int kpos = s >> 1;
    int ky = kpos / 3, kx = kpos % 3;
    float v = wc[(((size_t)oc * IC + ic) * 3 + ky) * 3 + kx];
    __hip_bfloat16 h = __float2bfloat16(v);
    Bt[t] = reinterpret_cast<unsigned short&>(h);
}

// ---------------------------------------------------------------------------
// Kernel B (byte-identical to R5/R6): bilinear sampling -> granule layout.
// ---------------------------------------------------------------------------
__global__ __launch_bounds__(256) void sample_g(const float* __restrict__ x,
                                                const float* __restrict__ off,
                                                unsigned short* __restrict__ xoff,
                                                int b0, int nwg) {
    int orig = blockIdx.x;
    int chunk = nwg >> 3;
    int wg = (orig & 7) * chunk + (orig >> 3);

    int xt  = wg % 12;
    int tmp = wg / 12;
    int yy  = tmp % XOF;
    int bl  = tmp / XOF;
    int b   = b0 + bl;
    int xx0 = xt * 32;

    int t  = threadIdx.x;
    int xl = t & 31;
    int cg = t >> 5;
    int xx = xx0 + xl;

    int j = xx / 3, kw = xx % 3;
    int i = yy / 3, kh = yy % 3;
    int n = kh * 3 + kw;

    const float* offb = off + (size_t)b * 18 * HH * WW + (size_t)i * WW + j;
    float offr = offb[(size_t)n * HH * WW];
    float offc = offb[(size_t)(n + 9) * HH * WW];

    float pr = (float)(i + kh) + offr;
    float pc = (float)(j + kw) + offc;

    float r0f = floorf(pr), c0f = floorf(pc);
    int r0 = min(max((int)r0f, 0), HP - 1);
    int c0 = min(max((int)c0f, 0), HP - 1);
    int r1 = min(max((int)(r0f + 1.f), 0), HP - 1);
    int c1 = min(max((int)(c0f + 1.f), 0), HP - 1);

    float prc = fminf(fmaxf(pr, 0.f), (float)(HP - 1));
    float pcc = fminf(fmaxf(pc, 0.f), (float)(HP - 1));

    float glt = (1.f + ((float)r0 - prc)) * (1.f + ((float)c0 - pcc));
    float grb = (1.f - ((float)r1 - prc)) * (1.f - ((float)c1 - pcc));
    float glb = (1.f + ((float)r0 - prc)) * (1.f - ((float)c1 - pcc));
    float grt = (1.f - ((float)r1 - prc)) * (1.f + ((float)c0 - pcc));

    int rr0 = r0 - 1, cc0 = c0 - 1, rr1 = r1 - 1, cc1 = c1 - 1;
    bool r0ok = (rr0 >= 0) && (rr0 < HH);
    bool r1ok = (rr1 >= 0) && (rr1 < HH);
    bool c0ok = (cc0 >= 0) && (cc0 < WW);
    bool c1ok = (cc1 >= 0) && (cc1 < WW);

    float wlt = (r0ok && c0ok) ? glt : 0.f;
    float wrb = (r1ok && c1ok) ? grb : 0.f;
    float wlb = (r0ok && c1ok) ? glb : 0.f;
    float wrt = (r1ok && c0ok) ? grt : 0.f;
    int olt = (r0ok && c0ok) ? (rr0 * WW + cc0) : 0;
    int orb = (r1ok && c1ok) ? (rr1 * WW + cc1) : 0;
    int olb = (r0ok && c1ok) ? (rr0 * WW + cc1) : 0;
    int ort = (r1ok && c0ok) ? (rr1 * WW + cc0) : 0;

    const float* xg = x + ((size_t)b * IC + cg * 8) * HH * WW;

    us8 res;
#pragma unroll
    for (int e = 0; e < 8; ++e) {
        const float* xc = xg + (size_t)e * HH * WW;
        float v = wlt * xc[olt] + wrb * xc[orb] + wlb * xc[olb] + wrt * xc[ort];
        __hip_bfloat16 h = __float2bfloat16(v);
        res[e] = reinterpret_cast<unsigned short&>(h);
    }

    size_t di = ((((size_t)bl * XOF + yy) * 8 + cg) * XPAD + xx) * 8;
    *(us8*)(xoff + di) = res;
}

// ---------------------------------------------------------------------------
// Kernel C (byte-identical to R4/R5/R6): bf16 MFMA implicit-GEMM conv.
// ---------------------------------------------------------------------------
__global__ __launch_bounds__(256) void conv2_mfma(const unsigned short* __restrict__ xoff,
                                                  const unsigned short* __restrict__ Bt,
                                                  float* __restrict__ out,
                                                  int b0, int nwg) {
    __shared__ __align__(16) char lds[40960];
    // A slab buf: [cg:4][px:192][16B] = 12288 B at buf*12288
    // B buf:      [kg:4][oc:128][16B] =  8192 B at 24576 + buf*8192

    // bijective XCD-chunk swizzle (m204)
    int orig = blockIdx.x;
    int q = nwg >> 3, r = nwg & 7;
    int xcd = orig & 7, loc = orig >> 3;
    int wgid = (xcd < r ? xcd * (q + 1) : r * (q + 1) + (xcd - r) * q) + loc;

    int xt  = wgid % 3;
    int tmp = wgid / 3;
    int oy  = tmp % OH2;
    int bl  = tmp / OH2;
    int x0  = xt << 7;

    int tid  = threadIdx.x;
    int wave = tid >> 6, lane = tid & 63;
    int wm = wave >> 1;            // px half
    int wn = wave & 1;             // oc half
    int lr = lane & 15, lc = lane >> 4;

    const char* xb = (const char*)xoff + (size_t)bl * ((size_t)XOF * 8 * XPAD * 16);
    const char* bt = (const char*)Bt;

    f32x4 acc[4][4];
#pragma unroll
    for (int mf = 0; mf < 4; ++mf)
#pragma unroll
        for (int nf = 0; nf < 4; ++nf)
            acc[mf][nf] = (f32x4){0.f, 0.f, 0.f, 0.f};

    auto stageA = [&](int abuf, int s6, int third) {
        int ky  = s6 >> 1;
        int ich = s6 & 1;
        int L   = third * 4 + wave;
        int cg  = L / 3, seg = L % 3;
        const char* src = xb +
            (((size_t)(oy + ky) * 8 + ich * 4 + cg) * XPAD + x0 + seg * 64 + lane) * 16;
        char* dst = lds + abuf * 12288 + (cg * 192 + seg * 64) * 16;
        gload16(src, dst);
    };
    auto stageA_full = [&](int abuf, int s6) {
#pragma unroll
        for (int qq = 0; qq < 3; ++qq) {
            int ky  = s6 >> 1;
            int ich = s6 & 1;
            int L   = wave * 3 + qq;
            int cg  = L / 3, seg = L % 3;
            const char* src = xb +
                (((size_t)(oy + ky) * 8 + ich * 4 + cg) * XPAD + x0 + seg * 64 + lane) * 16;
            char* dst = lds + abuf * 12288 + (cg * 192 + seg * 64) * 16;
            gload16(src, dst);
        }
    };
    auto stageB = [&](int bbuf, int t) {
        int s6 = t / 3, kx = t % 3;
        int sB = ((s6 >> 1) * 3 + kx) * 2 + (s6 & 1);
        const char* bsrc = bt + (size_t)sB * 8192;
#pragma unroll
        for (int g2 = 0; g2 < 2; ++g2) {
            int g = wave * 2 + g2;
            gload16(bsrc + (size_t)g * 1024 + lane * 16,
                    lds + 24576 + bbuf * 8192 + g * 1024);
        }
    };

    auto compute = [&](int abuf, int bbuf, int kx) {
        const char* abase = lds + abuf * 12288;
        const char* bbase = lds + 24576 + bbuf * 8192;
        bf16x8 af[4], bfr[4];
#pragma unroll
        for (int mf = 0; mf < 4; ++mf)
            af[mf] = *(const bf16x8*)(abase +
                (lc * 192 + wm * 64 + mf * 16 + lr + kx) * 16);
#pragma unroll
        for (int nf = 0; nf < 4; ++nf)
            bfr[nf] = *(const bf16x8*)(bbase +
                (lc * 128 + wn * 64 + nf * 16 + lr) * 16);
#pragma unroll
        for (int mf = 0; mf < 4; ++mf)
#pragma unroll
            for (int nf = 0; nf < 4; ++nf)
                acc[mf][nf] = __builtin_amdgcn_mfma_f32_16x16x32_bf16(
                    af[mf], bfr[nf], acc[mf][nf], 0, 0, 0);
    };

    stageA_full(0, 0);
    stageB(0, 0);
    __syncthreads();

    int abuf = 0, bbuf = 0;
    for (int t = 0; t < 18; ++t) {
        int s6 = t / 3, kx = t % 3;
        if (t + 1 < 18) stageB(bbuf ^ 1, t + 1);
        if (s6 + 1 < 6) stageA(abuf ^ 1, s6 + 1, kx);
        compute(abuf, bbuf, kx);
        __syncthreads();
        bbuf ^= 1;
        if (kx == 2) abuf ^= 1;
    }

    int b = b0 + bl;
#pragma unroll
    for (int mf = 0; mf < 4; ++mf) {
        int ox0 = x0 + wm * 64 + mf * 16 + (lc << 2);
#pragma unroll
        for (int nf = 0; nf < 4; ++nf) {
            int oc = wn * 64 + nf * 16 + lr;
            float* po = out + (((size_t)b * OC + oc) * OH2 + oy) * OH2 + ox0;
            if (ox0 + 3 < OH2) {
                *(f32x4u*)po = acc[mf][nf];
            } else {
#pragma unroll
                for (int rr = 0; rr < 4; ++rr)
                    if (ox0 + rr < OH2) po[rr] = acc[mf][nf][rr];
            }
        }
    }
}

// ---------------------------------------------------------------------------
extern "C" void kernel_launch(void* const* d_in, const int* in_sizes, int n_in,
                              void* d_out, int out_size, void* d_ws, size_t ws_size,
                              hipStream_t stream) {
    const float* x      = (const float*)d_in[0];
    const float* w_p    = (const float*)d_in[1];
    const float* b_p    = (const float*)d_in[2];
    const float* w_conv = (const float*)d_in[3];
    float* out = (float*)d_out;

    const size_t offElems = (size_t)B_ * 18 * HH * WW;          // f32
    const size_t btElems  = (size_t)18 * 4 * 128 * 8;           // bf16
    const size_t xofElems = (size_t)XOF * 8 * XPAD * 8;         // bf16 per batch
    const size_t slack    = 16384;

    float* off = (float*)d_ws;
    unsigned short* Bt   = (unsigned short*)(off + offElems);
    unsigned short* xoff = Bt + btElems;

    const size_t headBytes = offElems * 4 + btElems * 2;
    const bool allBatch = ws_size >= headBytes + 4 * xofElems * 2 + slack;

    prep_w<<<(int)((btElems + 255) / 256), 256, 0, stream>>>(w_conv, Bt);
    offset_conv<<<(B_ * HH * WW) / 256, 256, 0, stream>>>(x, w_p, b_p, off);

    if (allBatch) {
        int snwg = 12 * XOF * B_;                 // 18432
        sample_g<<<snwg, 256, 0, stream>>>(x, off, xoff, 0, snwg);
        int cnwg = 3 * OH2 * B_;                  // 4584
        conv2_mfma<<<cnwg, 256, 0, stream>>>(xoff, Bt, out, 0, cnwg);
    } else {
        for (int b = 0; b < B_; ++b) {
            int snwg = 12 * XOF;                  // 4608
            sample_g<<<snwg, 256, 0, stream>>>(x, off, xoff, b, snwg);
            int cnwg = 3 * OH2;                   // 1146
            conv2_mfma<<<cnwg, 256, 0, stream>>>(xoff, Bt, out, b, cnwg);
        }
    }
}